// Round 2
// baseline (208.905 us; speedup 1.0000x reference)
//
#include <hip/hip_runtime.h>
#include <stdint.h>

#define B_ 2
#define S_ 2048
#define D_ 512
#define H_ 8
#define HD_ 64
#define WIN_ 16
#define DIL_ 2
#define G_ 64
#define L_ (S_ - G_)   // 1984

typedef short bf16x8 __attribute__((ext_vector_type(8)));
typedef float f32x4 __attribute__((ext_vector_type(4)));
typedef unsigned short u16;

__device__ __forceinline__ float bf2f(u16 h) {
  return __uint_as_float(((uint32_t)h) << 16);
}
__device__ __forceinline__ u16 f2bf(float f) {
  uint32_t u = __float_as_uint(f);
  uint32_t r = (u + 0x7fffu + ((u >> 16) & 1u)) >> 16;
  return (u16)r;
}

// ---------------- convert fp32 -> bf16 ----------------
struct CvtJob { const float* src; u16* dst; int n4; };
struct CvtArgs { CvtJob job[9]; };

__global__ __launch_bounds__(256) void cvt_kernel(CvtArgs a) {
  CvtJob j = a.job[blockIdx.y];
  int stride = gridDim.x * blockDim.x;
  for (int i = blockIdx.x * blockDim.x + threadIdx.x; i < j.n4; i += stride) {
    float4 v = reinterpret_cast<const float4*>(j.src)[i];
    ushort4 o;
    o.x = f2bf(v.x); o.y = f2bf(v.y); o.z = f2bf(v.z); o.w = f2bf(v.w);
    reinterpret_cast<ushort4*>(j.dst)[i] = o;
  }
}

// ---------------- bf16 MFMA GEMM: Y = X @ W^T + bias ----------------
// X rows addressed as b*xbs + (xoff + r)*512 ; Y rows as b*ybs + (yoff + r)*512
// tile: BM=128 x BN=64, BK=32, 256 threads = 4 waves (2x2)
struct GemmArgs {
  const u16* X[3]; const u16* W[3]; const float* bias[3]; void* Y[3];
  int R;          // valid rows per batch
  int tiles_m;
  long xbs; int xoff;
  long ybs; int yoff;
};

template <int OUT_F32>
__global__ __launch_bounds__(256) void gemm_kernel(GemmArgs a) {
  const int z = blockIdx.z;
  const u16* X = a.X[z];
  const u16* W = a.W[z];
  const float* bias = a.bias[z];

  const int tm   = blockIdx.x % a.tiles_m;
  const int b    = blockIdx.x / a.tiles_m;
  const int n0   = blockIdx.y * 64;
  const int row0 = tm * 128;

  __shared__ __align__(16) u16 As[128 * 32];
  __shared__ __align__(16) u16 Bs[64 * 32];

  const int tid  = threadIdx.x;
  const int lane = tid & 63;
  const int wave = tid >> 6;
  const int wm = wave >> 1, wn = wave & 1;

  f32x4 acc[4][2];
#pragma unroll
  for (int i = 0; i < 4; ++i)
#pragma unroll
    for (int j = 0; j < 2; ++j) acc[i][j] = (f32x4){0.f, 0.f, 0.f, 0.f};

  const int srow = tid >> 2;        // 0..63
  const int akq  = (tid & 3) * 8;   // k sub-offset (elems)

  const int r1 = row0 + srow;
  const int r2 = row0 + 64 + srow;
  const int rr1 = r1 < a.R ? r1 : a.R - 1;
  const int rr2 = r2 < a.R ? r2 : a.R - 1;
  const size_t xrow1 = (size_t)b * a.xbs + (size_t)(a.xoff + rr1) * 512;
  const size_t xrow2 = (size_t)b * a.xbs + (size_t)(a.xoff + rr2) * 512;
  const size_t wrow  = (size_t)(n0 + srow) * 512;

  for (int kt = 0; kt < 16; ++kt) {
    const int k0 = kt * 32;
    int4 av1 = *(const int4*)&X[xrow1 + k0 + akq];
    int4 av2 = *(const int4*)&X[xrow2 + k0 + akq];
    int4 bv  = *(const int4*)&W[wrow + k0 + akq];
    __syncthreads();  // previous tile fully consumed
    *(int4*)&As[srow * 32 + akq]        = av1;
    *(int4*)&As[(64 + srow) * 32 + akq] = av2;
    *(int4*)&Bs[srow * 32 + akq]        = bv;
    __syncthreads();  // tile visible

    bf16x8 af[4], bfr[2];
#pragma unroll
    for (int fm = 0; fm < 4; ++fm)
      af[fm] = *(const bf16x8*)&As[(wm * 64 + fm * 16 + (lane & 15)) * 32 + 8 * (lane >> 4)];
#pragma unroll
    for (int fn = 0; fn < 2; ++fn)
      bfr[fn] = *(const bf16x8*)&Bs[(wn * 32 + fn * 16 + (lane & 15)) * 32 + 8 * (lane >> 4)];
#pragma unroll
    for (int fm = 0; fm < 4; ++fm)
#pragma unroll
      for (int fn = 0; fn < 2; ++fn)
        acc[fm][fn] = __builtin_amdgcn_mfma_f32_16x16x32_bf16(af[fm], bfr[fn], acc[fm][fn], 0, 0, 0);
  }

#pragma unroll
  for (int fm = 0; fm < 4; ++fm) {
#pragma unroll
    for (int fn = 0; fn < 2; ++fn) {
#pragma unroll
      for (int r = 0; r < 4; ++r) {
        const int row = row0 + wm * 64 + fm * 16 + (lane >> 4) * 4 + r;
        const int col = n0 + wn * 32 + fn * 16 + (lane & 15);
        if (row < a.R) {
          const float v = acc[fm][fn][r] + bias[col];
          const size_t yidx = (size_t)b * a.ybs + (size_t)(a.yoff + row) * 512 + col;
          if (OUT_F32) ((float*)a.Y[z])[yidx] = v;
          else         ((u16*)a.Y[z])[yidx]   = f2bf(v);
        }
      }
    }
  }
}

// ---------------- local sliding-window attention ----------------
// wave per (b,l,h): scores over 16 dilated window positions
__global__ __launch_bounds__(256) void attn_local(const u16* qp, const u16* kp,
                                                  const u16* vp, u16* o) {
  const int wid  = blockIdx.x * 4 + (threadIdx.x >> 6);
  const int lane = threadIdx.x & 63;
  const int h  = wid & 7;
  const int bl = wid >> 3;          // b*L + l
  const int l  = bl % L_;
  const size_t rowbase = (size_t)bl * 512 + h * 64;
  const size_t batch0  = (size_t)(bl - l) * 512;  // (b*L)*512

  const float q = bf2f(qp[rowbase + lane]);
  float s[WIN_];
#pragma unroll
  for (int w = 0; w < WIN_; ++w) {
    int ki = l + DIL_ * (w - WIN_ / 2);
    ki = ki < 0 ? 0 : (ki > L_ - 1 ? L_ - 1 : ki);
    float p = q * bf2f(kp[batch0 + (size_t)ki * 512 + h * 64 + lane]);
#pragma unroll
    for (int off = 32; off > 0; off >>= 1) p += __shfl_xor(p, off);
    s[w] = p * 0.125f;
  }
  float m = s[0];
#pragma unroll
  for (int w = 1; w < WIN_; ++w) m = fmaxf(m, s[w]);
  float sum = 0.f;
#pragma unroll
  for (int w = 0; w < WIN_; ++w) { s[w] = __expf(s[w] - m); sum += s[w]; }
  const float inv = 1.0f / sum;
  float acc = 0.f;
#pragma unroll
  for (int w = 0; w < WIN_; ++w) {
    int ki = l + DIL_ * (w - WIN_ / 2);
    ki = ki < 0 ? 0 : (ki > L_ - 1 ? L_ - 1 : ki);
    acc += s[w] * bf2f(vp[batch0 + (size_t)ki * 512 + h * 64 + lane]);
  }
  o[rowbase + lane] = f2bf(acc * inv);
}

// ---------------- global attention (64 tokens, full) ----------------
__global__ __launch_bounds__(256) void attn_global(const u16* qg, const u16* kg,
                                                   const u16* vg, u16* og) {
  const int wid  = blockIdx.x * 4 + (threadIdx.x >> 6);  // (b*8+h)*64 + qi
  const int lane = threadIdx.x & 63;
  const int qi = wid & 63;
  const int h  = (wid >> 6) & 7;
  const int b  = wid >> 9;

  const float q = bf2f(qg[(size_t)(b * 64 + qi) * 512 + h * 64 + lane]);
  float my = 0.f;
  for (int j = 0; j < 64; ++j) {
    float p = q * bf2f(kg[(size_t)(b * 64 + j) * 512 + h * 64 + lane]);
#pragma unroll
    for (int off = 32; off > 0; off >>= 1) p += __shfl_xor(p, off);
    if (lane == j) my = p * 0.125f;
  }
  float m = my;
#pragma unroll
  for (int off = 32; off > 0; off >>= 1) m = fmaxf(m, __shfl_xor(m, off));
  float e = __expf(my - m);
  float sum = e;
#pragma unroll
  for (int off = 32; off > 0; off >>= 1) sum += __shfl_xor(sum, off);
  const float p = e / sum;
  float acc = 0.f;
  for (int j = 0; j < 64; ++j) {
    float pj = __shfl(p, j);
    acc += pj * bf2f(vg[(size_t)(b * 64 + j) * 512 + h * 64 + lane]);
  }
  og[(size_t)(b * 64 + qi) * 512 + h * 64 + lane] = f2bf(acc);
}

// ---------------- host ----------------
extern "C" void kernel_launch(void* const* d_in, const int* in_sizes, int n_in,
                              void* d_out, int out_size, void* d_ws, size_t ws_size,
                              hipStream_t stream) {
  const float* query   = (const float*)d_in[0];
  const float* key     = (const float*)d_in[1];
  const float* value   = (const float*)d_in[2];
  const float* wq      = (const float*)d_in[3];
  const float* bq      = (const float*)d_in[4];
  const float* wk      = (const float*)d_in[5];
  const float* bk      = (const float*)d_in[6];
  const float* wv      = (const float*)d_in[7];
  const float* bv      = (const float*)d_in[8];
  const float* wo      = (const float*)d_in[9];
  const float* bo      = (const float*)d_in[10];
  const float* g_in_w  = (const float*)d_in[11];
  const float* g_in_b  = (const float*)d_in[12];
  const float* g_out_w = (const float*)d_in[13];
  const float* g_out_b = (const float*)d_in[14];
  float* out = (float*)d_out;

  u16* w16 = (u16*)d_ws;
  const size_t QKV = (size_t)B_ * S_ * D_;   // 2097152
  const size_t WSZ = (size_t)D_ * D_;        // 262144
  const size_t PSZ = (size_t)B_ * L_ * D_;   // 2031616
  const size_t GSZ = (size_t)B_ * G_ * D_;   // 65536

  u16* qb  = w16;              u16* kb  = qb + QKV;   u16* vb  = kb + QKV;
  u16* wqb = vb + QKV;         u16* wkb = wqb + WSZ;  u16* wvb = wkb + WSZ;
  u16* wob = wvb + WSZ;
  u16* gqw = wob + WSZ;        u16* gkw = gqw + WSZ;  u16* gvw = gkw + WSZ;
  u16* gow = gvw + WSZ;
  u16* qp  = gow + WSZ;        u16* kp  = qp + PSZ;   u16* vp  = kp + PSZ;
  u16* ob  = vp + PSZ;
  u16* qgp = ob + PSZ;         u16* kgp = qgp + GSZ;  u16* vgp = kgp + GSZ;
  u16* ogp = vgp + GSZ;

  // 1) convert inputs to bf16
  CvtArgs ca;
  ca.job[0] = {query, qb, (int)(QKV / 4)};
  ca.job[1] = {key,   kb, (int)(QKV / 4)};
  ca.job[2] = {value, vb, (int)(QKV / 4)};
  ca.job[3] = {wq, wqb, (int)(WSZ / 4)};
  ca.job[4] = {wk, wkb, (int)(WSZ / 4)};
  ca.job[5] = {wv, wvb, (int)(WSZ / 4)};
  ca.job[6] = {wo, wob, (int)(WSZ / 4)};
  ca.job[7] = {g_in_w, gqw, (int)(3 * WSZ / 4)};   // covers gqw,gkw,gvw
  ca.job[8] = {g_out_w, gow, (int)(WSZ / 4)};
  hipLaunchKernelGGL(cvt_kernel, dim3(512, 9), dim3(256), 0, stream, ca);

  // 2) local projections (q,k,v) for rows G..S-1
  GemmArgs pl;
  pl.X[0] = qb; pl.X[1] = kb; pl.X[2] = vb;
  pl.W[0] = wqb; pl.W[1] = wkb; pl.W[2] = wvb;
  pl.bias[0] = bq; pl.bias[1] = bk; pl.bias[2] = bv;
  pl.Y[0] = qp; pl.Y[1] = kp; pl.Y[2] = vp;
  pl.R = L_; pl.tiles_m = 16;
  pl.xbs = (long)S_ * D_; pl.xoff = G_;
  pl.ybs = (long)L_ * D_; pl.yoff = 0;
  hipLaunchKernelGGL(gemm_kernel<0>, dim3(32, 8, 3), dim3(256), 0, stream, pl);

  // 3) global projections (first G rows, g_in_w slices)
  GemmArgs pg;
  pg.X[0] = qb; pg.X[1] = kb; pg.X[2] = vb;
  pg.W[0] = gqw; pg.W[1] = gkw; pg.W[2] = gvw;
  pg.bias[0] = g_in_b; pg.bias[1] = g_in_b + D_; pg.bias[2] = g_in_b + 2 * D_;
  pg.Y[0] = qgp; pg.Y[1] = kgp; pg.Y[2] = vgp;
  pg.R = G_; pg.tiles_m = 1;
  pg.xbs = (long)S_ * D_; pg.xoff = 0;
  pg.ybs = (long)G_ * D_; pg.yoff = 0;
  hipLaunchKernelGGL(gemm_kernel<0>, dim3(2, 8, 3), dim3(256), 0, stream, pg);

  // 4) attentions
  hipLaunchKernelGGL(attn_local, dim3(B_ * L_ * H_ / 4), dim3(256), 0, stream, qp, kp, vp, ob);
  hipLaunchKernelGGL(attn_global, dim3(B_ * G_ * H_ / 4), dim3(256), 0, stream, qgp, kgp, vgp, ogp);

  // 5) output projections into d_out
  GemmArgs ol;
  ol.X[0] = ol.X[1] = ol.X[2] = ob;
  ol.W[0] = ol.W[1] = ol.W[2] = wob;
  ol.bias[0] = ol.bias[1] = ol.bias[2] = bo;
  ol.Y[0] = ol.Y[1] = ol.Y[2] = out;
  ol.R = L_; ol.tiles_m = 16;
  ol.xbs = (long)L_ * D_; ol.xoff = 0;
  ol.ybs = (long)S_ * D_; ol.yoff = G_;
  hipLaunchKernelGGL(gemm_kernel<1>, dim3(32, 8, 1), dim3(256), 0, stream, ol);

  GemmArgs og;
  og.X[0] = og.X[1] = og.X[2] = ogp;
  og.W[0] = og.W[1] = og.W[2] = gow;
  og.bias[0] = og.bias[1] = og.bias[2] = g_out_b;
  og.Y[0] = og.Y[1] = og.Y[2] = out;
  og.R = G_; og.tiles_m = 1;
  og.xbs = (long)G_ * D_; og.xoff = 0;
  og.ybs = (long)S_ * D_; og.yoff = 0;
  hipLaunchKernelGGL(gemm_kernel<1>, dim3(2, 8, 1), dim3(256), 0, stream, og);
}

// Round 3
// 177.498 us; speedup vs baseline: 1.1769x; 1.1769x over previous
//
#include <hip/hip_runtime.h>
#include <stdint.h>

#define B_ 2
#define S_ 2048
#define D_ 512
#define H_ 8
#define WIN_ 16
#define DIL_ 2
#define G_ 64
#define L_ (S_ - G_)   // 1984;  B_*L_ = 3968 = 31*128 exactly

typedef short bf16x8 __attribute__((ext_vector_type(8)));
typedef float f32x4 __attribute__((ext_vector_type(4)));
typedef unsigned short u16;

__device__ __forceinline__ float bf2f(u16 h) {
  return __uint_as_float(((uint32_t)h) << 16);
}
__device__ __forceinline__ u16 f2bf(float f) {
  uint32_t u = __float_as_uint(f);
  uint32_t r = (u + 0x7fffu + ((u >> 16) & 1u)) >> 16;
  return (u16)r;
}

__device__ __forceinline__ void gload16(const u16* g, u16* l) {
  __builtin_amdgcn_global_load_lds(
      (const __attribute__((address_space(1))) void*)g,
      (__attribute__((address_space(3))) void*)l, 16, 0, 0);
}

// ---------------- convert fp32 -> bf16 ----------------
struct CvtJob { const float* src; u16* dst; int n4; };
struct CvtArgs { CvtJob job[9]; };

__global__ __launch_bounds__(256) void cvt_kernel(CvtArgs a) {
  CvtJob j = a.job[blockIdx.y];
  int stride = gridDim.x * blockDim.x;
  for (int i = blockIdx.x * blockDim.x + threadIdx.x; i < j.n4; i += stride) {
    float4 v = reinterpret_cast<const float4*>(j.src)[i];
    ushort4 o;
    o.x = f2bf(v.x); o.y = f2bf(v.y); o.z = f2bf(v.z); o.w = f2bf(v.w);
    reinterpret_cast<ushort4*>(j.dst)[i] = o;
  }
}

// ---------------- unified bf16 MFMA GEMM: Y = X @ W^T + bias ----------------
// M = 2*rpb flattened rows; tile BM=128 x BN=64, BK=32; K=N=512 fixed.
// 256 threads = 4 waves (2x2), global_load_lds width-16 staging.
struct Job {
  const u16* X; const u16* W; const float* bias; void* Y;
  int rpb;     // rows per batch (M = 2*rpb)
  int xoff;    // X row offset within batch
  long xbs;    // X batch stride (elems)
  int yoff;    // Y row offset within batch
  long ybs;    // Y batch stride (elems)
  int out_f32;
};
struct GemmLaunch { int start[6]; Job job[6]; };

__global__ __launch_bounds__(256) void gemm_kernel(GemmLaunch a) {
  int j = 0;
#pragma unroll
  for (int i = 1; i < 6; ++i) j = ((int)blockIdx.x >= a.start[i]) ? i : j;
  const Job jb = a.job[j];
  const int bid = blockIdx.x - a.start[j];
  const int tm = bid >> 3, tn = bid & 7;     // ntiles_n = 512/64 = 8
  const int row0 = tm * 128, n0 = tn * 64;

  __shared__ __align__(16) u16 As[128 * 32];  // 8 KB
  __shared__ __align__(16) u16 Bs[64 * 32];   // 4 KB

  const int tid = threadIdx.x, lane = tid & 63, w = tid >> 6;
  const int wm = w >> 1, wn = w & 1;

  // staging: thread covers A rows {row0 + w*16 + lane/4, +64}, B row n0 + same,
  // k-chunk (lane&3)*8.  LDS dest base is wave-uniform (HW adds lane*16B).
  const int rA = w * 16 + (lane >> 2);
  const int kq = (lane & 3) * 8;

  const int ra0 = row0 + rA,        ba0 = ra0 >= jb.rpb;
  const int ra1 = row0 + 64 + rA,   ba1 = ra1 >= jb.rpb;
  const u16* xa0 = jb.X + (size_t)(ba0 ? jb.xbs : 0) +
                   (size_t)(jb.xoff + ra0 - (ba0 ? jb.rpb : 0)) * 512 + kq;
  const u16* xa1 = jb.X + (size_t)(ba1 ? jb.xbs : 0) +
                   (size_t)(jb.xoff + ra1 - (ba1 ? jb.rpb : 0)) * 512 + kq;
  const u16* wb  = jb.W + (size_t)(n0 + rA) * 512 + kq;
  u16* la0 = As + w * 512;
  u16* la1 = As + 2048 + w * 512;
  u16* lb  = Bs + w * 512;

  f32x4 acc[4][2];
#pragma unroll
  for (int i = 0; i < 4; ++i)
#pragma unroll
    for (int k = 0; k < 2; ++k) acc[i][k] = (f32x4){0.f, 0.f, 0.f, 0.f};

  for (int kt = 0; kt < 16; ++kt) {
    gload16(xa0, la0);
    gload16(xa1, la1);
    gload16(wb,  lb);
    xa0 += 32; xa1 += 32; wb += 32;
    __syncthreads();   // drain vmcnt -> tile visible

    bf16x8 af[4], bfr[2];
#pragma unroll
    for (int fm = 0; fm < 4; ++fm)
      af[fm] = *(const bf16x8*)&As[(wm * 64 + fm * 16 + (lane & 15)) * 32 + 8 * (lane >> 4)];
#pragma unroll
    for (int fn = 0; fn < 2; ++fn)
      bfr[fn] = *(const bf16x8*)&Bs[(wn * 32 + fn * 16 + (lane & 15)) * 32 + 8 * (lane >> 4)];
#pragma unroll
    for (int fm = 0; fm < 4; ++fm)
#pragma unroll
      for (int fn = 0; fn < 2; ++fn)
        acc[fm][fn] = __builtin_amdgcn_mfma_f32_16x16x32_bf16(af[fm], bfr[fn], acc[fm][fn], 0, 0, 0);
    __syncthreads();   // tile consumed before overwrite
  }

#pragma unroll
  for (int fm = 0; fm < 4; ++fm) {
#pragma unroll
    for (int fn = 0; fn < 2; ++fn) {
#pragma unroll
      for (int r = 0; r < 4; ++r) {
        const int row = row0 + wm * 64 + fm * 16 + (lane >> 4) * 4 + r;
        const int col = n0 + wn * 32 + fn * 16 + (lane & 15);
        const int b = row >= jb.rpb;
        const int rr = row - (b ? jb.rpb : 0);
        const size_t yi = (size_t)(b ? jb.ybs : 0) + (size_t)(jb.yoff + rr) * 512 + col;
        const float v = acc[fm][fn][r] + jb.bias[col];
        if (jb.out_f32) ((float*)jb.Y)[yi] = v;
        else            ((u16*)jb.Y)[yi]   = f2bf(v);
      }
    }
  }
}

// ---------------- fused attention (local windowed + global) ----------------
// wave per (b,l) for local: lane owns 8 contiguous elems of the 512-row
// (head = lane>>3); per-head dot via 3-level shfl_xor within 8-lane groups.
// waves [B*L .. B*L+128) do global attention, wave per (b,qi).
__global__ __launch_bounds__(256) void attn_kernel(const u16* qp, const u16* kp,
                                                   const u16* vp, u16* ob,
                                                   const u16* qgp, const u16* kgp,
                                                   const u16* vgp, u16* ogp) {
  const int lane = threadIdx.x & 63;
  const int wid = blockIdx.x * 4 + (threadIdx.x >> 6);

  if (wid < B_ * L_) {
    const int l = wid % L_;
    const int brow = wid - l;   // batch base row
    float q[8];
    {
      bf16x8 qv = *(const bf16x8*)&qp[(size_t)wid * 512 + lane * 8];
#pragma unroll
      for (int e = 0; e < 8; ++e) q[e] = bf2f((u16)qv[e]);
    }
    float s[WIN_];
#pragma unroll
    for (int w2 = 0; w2 < WIN_; ++w2) {
      int ki = l + DIL_ * w2 - WIN_;
      ki = ki < 0 ? 0 : (ki > L_ - 1 ? L_ - 1 : ki);
      bf16x8 kv = *(const bf16x8*)&kp[(size_t)(brow + ki) * 512 + lane * 8];
      float p = 0.f;
#pragma unroll
      for (int e = 0; e < 8; ++e) p = fmaf(q[e], bf2f((u16)kv[e]), p);
      p += __shfl_xor(p, 1); p += __shfl_xor(p, 2); p += __shfl_xor(p, 4);
      s[w2] = p * 0.125f;
    }
    float m = s[0];
#pragma unroll
    for (int w2 = 1; w2 < WIN_; ++w2) m = fmaxf(m, s[w2]);
    float sum = 0.f;
#pragma unroll
    for (int w2 = 0; w2 < WIN_; ++w2) { s[w2] = __expf(s[w2] - m); sum += s[w2]; }
    const float inv = 1.0f / sum;
    float acc[8] = {0.f};
#pragma unroll
    for (int w2 = 0; w2 < WIN_; ++w2) {
      int ki = l + DIL_ * w2 - WIN_;
      ki = ki < 0 ? 0 : (ki > L_ - 1 ? L_ - 1 : ki);
      bf16x8 vv = *(const bf16x8*)&vp[(size_t)(brow + ki) * 512 + lane * 8];
#pragma unroll
      for (int e = 0; e < 8; ++e) acc[e] = fmaf(s[w2], bf2f((u16)vv[e]), acc[e]);
    }
    bf16x8 o8;
#pragma unroll
    for (int e = 0; e < 8; ++e) o8[e] = (short)f2bf(acc[e] * inv);
    *(bf16x8*)&ob[(size_t)wid * 512 + lane * 8] = o8;
  } else {
    const int g = wid - B_ * L_;         // 0..127
    const int base = (g >> 6) * 64;      // b*64
    const int qi = g & 63;
    float q[8];
    {
      bf16x8 qv = *(const bf16x8*)&qgp[(size_t)(base + qi) * 512 + lane * 8];
#pragma unroll
      for (int e = 0; e < 8; ++e) q[e] = bf2f((u16)qv[e]);
    }
    float m = -1e30f, sum = 0.f, acc[8] = {0.f};
    for (int j2 = 0; j2 < 64; ++j2) {
      bf16x8 kv = *(const bf16x8*)&kgp[(size_t)(base + j2) * 512 + lane * 8];
      float p = 0.f;
#pragma unroll
      for (int e = 0; e < 8; ++e) p = fmaf(q[e], bf2f((u16)kv[e]), p);
      p += __shfl_xor(p, 1); p += __shfl_xor(p, 2); p += __shfl_xor(p, 4);
      p *= 0.125f;
      const float mn = fmaxf(m, p);
      const float c  = __expf(m - mn);
      const float pe = __expf(p - mn);
      sum = sum * c + pe;
      m = mn;
      bf16x8 vv = *(const bf16x8*)&vgp[(size_t)(base + j2) * 512 + lane * 8];
#pragma unroll
      for (int e = 0; e < 8; ++e) acc[e] = fmaf(acc[e], c, 0.f) + pe * bf2f((u16)vv[e]);
    }
    const float inv = 1.0f / sum;
    bf16x8 o8;
#pragma unroll
    for (int e = 0; e < 8; ++e) o8[e] = (short)f2bf(acc[e] * inv);
    *(bf16x8*)&ogp[(size_t)(base + qi) * 512 + lane * 8] = o8;
  }
}

// ---------------- host ----------------
extern "C" void kernel_launch(void* const* d_in, const int* in_sizes, int n_in,
                              void* d_out, int out_size, void* d_ws, size_t ws_size,
                              hipStream_t stream) {
  const float* query   = (const float*)d_in[0];
  const float* key     = (const float*)d_in[1];
  const float* value   = (const float*)d_in[2];
  const float* wq      = (const float*)d_in[3];
  const float* bq      = (const float*)d_in[4];
  const float* wk      = (const float*)d_in[5];
  const float* bk      = (const float*)d_in[6];
  const float* wv      = (const float*)d_in[7];
  const float* bv      = (const float*)d_in[8];
  const float* wo      = (const float*)d_in[9];
  const float* bo      = (const float*)d_in[10];
  const float* g_in_w  = (const float*)d_in[11];
  const float* g_in_b  = (const float*)d_in[12];
  const float* g_out_w = (const float*)d_in[13];
  const float* g_out_b = (const float*)d_in[14];
  float* out = (float*)d_out;

  u16* w16 = (u16*)d_ws;
  const size_t QKV = (size_t)B_ * S_ * D_;   // 2097152
  const size_t WSZ = (size_t)D_ * D_;        // 262144
  const size_t PSZ = (size_t)B_ * L_ * D_;   // 2031616
  const size_t GSZ = (size_t)B_ * G_ * D_;   // 65536

  u16* qb  = w16;              u16* kb  = qb + QKV;   u16* vb  = kb + QKV;
  u16* wqb = vb + QKV;         u16* wkb = wqb + WSZ;  u16* wvb = wkb + WSZ;
  u16* wob = wvb + WSZ;
  u16* gqw = wob + WSZ;        u16* gkw = gqw + WSZ;  u16* gvw = gkw + WSZ;
  u16* gow = gvw + WSZ;
  u16* qp  = gow + WSZ;        u16* kp  = qp + PSZ;   u16* vp  = kp + PSZ;
  u16* ob  = vp + PSZ;
  u16* qgp = ob + PSZ;         u16* kgp = qgp + GSZ;  u16* vgp = kgp + GSZ;
  u16* ogp = vgp + GSZ;

  // 1) convert inputs to bf16
  CvtArgs ca;
  ca.job[0] = {query, qb, (int)(QKV / 4)};
  ca.job[1] = {key,   kb, (int)(QKV / 4)};
  ca.job[2] = {value, vb, (int)(QKV / 4)};
  ca.job[3] = {wq, wqb, (int)(WSZ / 4)};
  ca.job[4] = {wk, wkb, (int)(WSZ / 4)};
  ca.job[5] = {wv, wvb, (int)(WSZ / 4)};
  ca.job[6] = {wo, wob, (int)(WSZ / 4)};
  ca.job[7] = {g_in_w, gqw, (int)(3 * WSZ / 4)};   // covers gqw,gkw,gvw
  ca.job[8] = {g_out_w, gow, (int)(WSZ / 4)};
  hipLaunchKernelGGL(cvt_kernel, dim3(512, 9), dim3(256), 0, stream, ca);

  const long XBS = (long)S_ * D_;   // 1048576
  const long PBS = (long)L_ * D_;   // 1015808
  const long GBS = (long)G_ * D_;   // 32768

  // 2) input projections: 3 local jobs (31 mtiles * 8 = 248 blocks each)
  //    + 3 global jobs (1 mtile * 8 = 8 blocks each) = 768 blocks total
  GemmLaunch gi;
  gi.start[0] = 0; gi.start[1] = 248; gi.start[2] = 496;
  gi.start[3] = 744; gi.start[4] = 752; gi.start[5] = 760;
  gi.job[0] = {qb, wqb, bq, qp, L_, G_, XBS, 0, PBS, 0};
  gi.job[1] = {kb, wkb, bk, kp, L_, G_, XBS, 0, PBS, 0};
  gi.job[2] = {vb, wvb, bv, vp, L_, G_, XBS, 0, PBS, 0};
  gi.job[3] = {qb, gqw, g_in_b,           qgp, G_, 0, XBS, 0, GBS, 0};
  gi.job[4] = {kb, gkw, g_in_b + D_,      kgp, G_, 0, XBS, 0, GBS, 0};
  gi.job[5] = {vb, gvw, g_in_b + 2 * D_,  vgp, G_, 0, XBS, 0, GBS, 0};
  hipLaunchKernelGGL(gemm_kernel, dim3(768), dim3(256), 0, stream, gi);

  // 3) fused attention: 992 local blocks + 32 global blocks
  hipLaunchKernelGGL(attn_kernel, dim3((B_ * L_ + 128) / 4), dim3(256), 0, stream,
                     qp, kp, vp, ob, qgp, kgp, vgp, ogp);

  // 4) output projections: local (248 blocks) + global (8 blocks) = 256
  GemmLaunch go;
  go.start[0] = 0; go.start[1] = 248;
  go.start[2] = go.start[3] = go.start[4] = go.start[5] = 0x7fffffff;
  go.job[0] = {ob,  wob, bo,      out, L_, 0, PBS, G_, XBS, 1};
  go.job[1] = {ogp, gow, g_out_b, out, G_, 0, GBS, 0,  XBS, 1};
  go.job[2] = go.job[0]; go.job[3] = go.job[0]; go.job[4] = go.job[0]; go.job[5] = go.job[0];
  hipLaunchKernelGGL(gemm_kernel, dim3(256), dim3(256), 0, stream, go);
}